// Round 1
// 773.306 us; speedup vs baseline: 1.0499x; 1.0499x over previous
//
#include <hip/hip_runtime.h>
#include <math.h>

#define NIMG 16
#define A_ 3
#define H_ 160
#define W_ 160
#define C_ 80
#define HW_ (H_*W_)        // 25600
#define P_ (HW_*A_)        // 76800
#define K1 4096
#define K2 300
#define CAND_CAP 8192
#define IMGMAX 639.0f
#define BBOX_CLIP 4.135166556742356f  // log(1000/16)
// 0.5 + 2^-26, exact in double. RN32(inter/denom) > 0.5  <=>  denom>0 && inter > denom*THR (exact)
#define IOU_THR (0.5 + 1.0/67108864.0)

#define RING_ROWS 128
#define GRP 16
#define NGRP (K1/GRP)      // 256
#define NTRI 2080          // 64*65/2 wave-tiles per image
#define TRI_BLOCKS 520     // NTRI / 4 waves

__device__ __forceinline__ unsigned int f2key(float x) {
    unsigned int u = __float_as_uint(x);
    return (u & 0x80000000u) ? ~u : (u | 0x80000000u);
}
__device__ __forceinline__ float key2f(unsigned int k) {
    unsigned int u = (k & 0x80000000u) ? (k & 0x7FFFFFFFu) : ~k;
    return __uint_as_float(u);
}

// =====================================================================
// S1: per-image histogram of top-12 key bits, LDS-aggregated.
// grid: 240 blocks x 256 (15 blocks/image, 5120 items each)
// =====================================================================
__global__ __launch_bounds__(256) void k_hist(
        const float* __restrict__ obj, unsigned int* __restrict__ hist) {
    const int n = blockIdx.x / 15;
    const int chunk = blockIdx.x % 15;
    __shared__ unsigned int lh[4096];
    const int tid = threadIdx.x;
    for (int i = tid; i < 4096; i += 256) lh[i] = 0;
    __syncthreads();
    const float* o = obj + (size_t)n * P_ + chunk * 5120;
    for (int q = tid; q < 5120; q += 256) {
        unsigned int k = f2key(o[q]);
        atomicAdd(&lh[k >> 20], 1u);
    }
    __syncthreads();
    for (int i = tid; i < 4096; i += 256) {
        unsigned int v = lh[i];
        if (v) atomicAdd(&hist[n * 4096 + i], v);
    }
}

// =====================================================================
// S2: per-image threshold bucket via wave suffix-scan. 16 blocks x 64.
// =====================================================================
__global__ __launch_bounds__(64) void k_thresh(
        const unsigned int* __restrict__ hist, unsigned int* __restrict__ Tarr) {
    const int n = blockIdx.x, lane = threadIdx.x;
    const unsigned int* h = hist + n * 4096;
    unsigned int s = 0;
    for (int m = 0; m < 64; ++m) s += h[lane * 64 + m];
    unsigned int t = s;
    for (int off = 1; off < 64; off <<= 1) {
        unsigned int u = __shfl_down(t, off);
        if (lane + off < 64) t += u;
    }
    bool cond = (t >= (unsigned)K1) && (t - s < (unsigned)K1);
    unsigned long long bal = __ballot(cond);
    int cs = __builtin_ctzll(bal);
    unsigned int suf = __shfl(t - s, cs);
    unsigned int h2 = h[cs * 64 + lane];
    unsigned int t2 = h2;
    for (int off = 1; off < 64; off <<= 1) {
        unsigned int u = __shfl_down(t2, off);
        if (lane + off < 64) t2 += u;
    }
    bool cond2 = (suf + t2 >= (unsigned)K1) && (suf + t2 - h2 < (unsigned)K1);
    if (cond2) Tarr[n] = ((unsigned int)(cs * 64 + lane)) << 20;
}

// =====================================================================
// S3: compaction, block-aggregated atomics (1 global RMW per block).
// grid: 1200 blocks x 1024
// =====================================================================
__global__ __launch_bounds__(1024) void k_compact(
        const float* __restrict__ obj, const unsigned int* __restrict__ Tarr,
        unsigned long long* __restrict__ cand, unsigned int* __restrict__ cnt) {
    const int n = blockIdx.x / 75;
    const int q = (blockIdx.x % 75) * 1024 + threadIdx.x;
    const unsigned int T = Tarr[n];
    unsigned int k = f2key(obj[(size_t)n * P_ + q]);
    bool pred = (k >= T);
    const int lane = threadIdx.x & 63, wv = threadIdx.x >> 6;
    unsigned long long m = __ballot(pred);
    __shared__ unsigned int s_wbase[16];
    __shared__ unsigned int s_cnt, s_start;
    if (threadIdx.x == 0) s_cnt = 0;
    __syncthreads();
    if (lane == 0) s_wbase[wv] = atomicAdd(&s_cnt, (unsigned int)__popcll(m));
    __syncthreads();
    if (threadIdx.x == 0) s_start = atomicAdd(&cnt[n], s_cnt);
    __syncthreads();
    if (pred) {
        unsigned int pos = s_start + s_wbase[wv] +
                           (unsigned int)__popcll(m & ((1ull << lane) - 1ull));
        if (pos < CAND_CAP) {
            unsigned int p = (unsigned int)((q % HW_) * A_ + (q / HW_));
            cand[(size_t)n * CAND_CAP + pos] =
                ((unsigned long long)(~k) << 32) | (unsigned long long)p;
        }
    }
}

// =====================================================================
// K_sort: segment-mapped bitonic. Wave w owns items [512w, 512w+512);
// stages with j<512 are wave-local (no barrier). 16 blocks x 1024.
// =====================================================================
__global__ __launch_bounds__(1024) void k_sort(
        const unsigned long long* __restrict__ cand,
        const unsigned int* __restrict__ cnt,
        unsigned int* __restrict__ sidx, float* __restrict__ sscore) {
    const int n = blockIdx.x;
    __shared__ unsigned long long S[CAND_CAP];   // 64 KB
    const int tid = threadIdx.x;
    const int wv = tid >> 6, lane = tid & 63;
    const int seg = wv * 512;
    unsigned int c = cnt[n]; if (c > CAND_CAP) c = CAND_CAP;
    #pragma unroll
    for (int m = 0; m < 8; ++m) {
        int t = seg + m * 64 + lane;
        S[t] = (t < (int)c) ? cand[(size_t)n * CAND_CAP + t] : 0xFFFFFFFFFFFFFFFFull;
    }
    int prevCross = 1;   // force barrier at first stage (covers load visibility)
    for (int k = 2; k <= CAND_CAP; k <<= 1) {
        for (int j = k >> 1; j > 0; j >>= 1) {
            int cross = (j >= 512);
            if (cross || prevCross) __syncthreads();
            #pragma unroll
            for (int m = 0; m < 8; ++m) {
                int t = seg + m * 64 + lane;
                int ixj = t ^ j;
                if (ixj > t) {
                    unsigned long long a = S[t], b = S[ixj];
                    bool up = ((t & k) == 0);
                    if ((a > b) == up) { S[t] = b; S[ixj] = a; }
                }
            }
            prevCross = cross;
        }
    }
    if (wv < 8) {
        #pragma unroll
        for (int m = 0; m < 8; ++m) {
            int t = seg + m * 64 + lane;
            unsigned long long s = S[t];
            sidx[(size_t)n * K1 + t] = (unsigned int)s;
            float x = key2f(~(unsigned int)(s >> 32));
            sscore[(size_t)n * K1 + t] = 1.0f / (1.0f + expf(-x));
        }
    }
}

// =====================================================================
// K_decode: analytic anchors + decode + clip + area. 256 blocks x 256.
// =====================================================================
__global__ __launch_bounds__(256) void k_decode(
        const unsigned int* __restrict__ sidx, const float* __restrict__ reg,
        float* __restrict__ bx1, float* __restrict__ by1,
        float* __restrict__ bx2, float* __restrict__ by2,
        float* __restrict__ bar) {
#pragma clang fp contract(off)
    const int gid = blockIdx.x * 256 + threadIdx.x;
    const int n = gid >> 12;
    const unsigned int p = sidx[gid];
    const int a  = (int)(p % 3u);
    const int hw = (int)(p / 3u);
    const int hh = hw / W_, ww = hw % W_;

    const float* rb = reg + ((size_t)n * 12 + a * 4) * HW_ + hw;
    float dx = rb[0];
    float dy = rb[HW_];
    float dw = rb[2 * HW_];
    float dh = rb[3 * HW_];

    const int half = 16 << a;
    float a0 = (float)(4 * ww + 2 - half);
    float a1 = (float)(4 * hh + 2 - half);
    float a2 = (float)(4 * ww + 2 + half - 1);
    float a3 = (float)(4 * hh + 2 + half - 1);

    float w  = a2 - a0 + 1.0f;
    float h  = a3 - a1 + 1.0f;
    float cx = a0 + 0.5f * w;
    float cy = a1 + 0.5f * h;
    float dwc = fminf(dw, BBOX_CLIP);
    float dhc = fminf(dh, BBOX_CLIP);
    float pcx = dx * w + cx;
    float pcy = dy * h + cy;
    float pw  = expf(dwc) * w;
    float ph  = expf(dhc) * h;
    float x1 = pcx - 0.5f * pw;
    float y1 = pcy - 0.5f * ph;
    float x2 = pcx + 0.5f * pw - 1.0f;
    float y2 = pcy + 0.5f * ph - 1.0f;
    x1 = fminf(fmaxf(x1, 0.0f), IMGMAX);
    y1 = fminf(fmaxf(y1, 0.0f), IMGMAX);
    x2 = fminf(fmaxf(x2, 0.0f), IMGMAX);
    y2 = fminf(fmaxf(y2, 0.0f), IMGMAX);
    bx1[gid] = x1; by1[gid] = y1; bx2[gid] = x2; by2[gid] = y2;
    bar[gid] = (x2 - x1 + 1.0f) * (y2 - y1 + 1.0f);   // reference area order
}

// =====================================================================
// K_iou v2: triangular per-wave tiling, lane = COLUMN.
// Wave tile t in [0,2080) -> (cw, R) with R <= cw. Column boxes live in
// registers (coalesced load once); row boxes are wave-uniform loads
// (readfirstlane -> scalar path); per-row mask = __ballot. No LDS, no
// barrier. mat is WORD-MAJOR: mat[n][word][row] -> wave's 64 row-masks
// store as one contiguous 512B coalesced write.
// grid: NIMG*520 blocks x 256 (4 waves/block)
// =====================================================================
__global__ __launch_bounds__(256) void k_iou(
        const float* __restrict__ bx1, const float* __restrict__ by1,
        const float* __restrict__ bx2, const float* __restrict__ by2,
        const float* __restrict__ bar,
        unsigned long long* __restrict__ mat) {
#pragma clang fp contract(off)
    const int b = blockIdx.x;
    const int n = b / TRI_BLOCKS;
    const int lane = threadIdx.x & 63, wv = threadIdx.x >> 6;
    const int t = (b % TRI_BLOCKS) * 4 + wv;            // 0..2079, wave-uniform
    int cw = (int)((sqrtf(8.0f * (float)t + 1.0f) - 1.0f) * 0.5f);
    while (cw * (cw + 1) / 2 > t) --cw;
    while ((cw + 1) * (cw + 2) / 2 <= t) ++cw;
    int R = t - cw * (cw + 1) / 2;                      // 0..cw
    cw = __builtin_amdgcn_readfirstlane(cw);
    R  = __builtin_amdgcn_readfirstlane(R);

    const size_t nb = (size_t)n * K1;
    const int col = cw * 64 + lane;
    const float cx1 = bx1[nb + col];
    const float cy1 = by1[nb + col];
    const float cx2 = bx2[nb + col];
    const float cy2 = by2[nb + col];
    const float ca  = bar[nb + col];

    const int rbase = R * 64;
    unsigned long long myword = 0ull;
    #pragma unroll 4
    for (int j = 0; j < 64; ++j) {
        const int r = rbase + j;                        // wave-uniform
        const float rx1 = bx1[nb + r];
        const float ry1 = by1[nb + r];
        const float rx2 = bx2[nb + r];
        const float ry2 = by2[nb + r];
        const float ra  = bar[nb + r];
        float iw = fminf(rx2, cx2) - fmaxf(rx1, cx1) + 1.0f;
        float ih = fminf(ry2, cy2) - fmaxf(ry1, cy1) + 1.0f;
        iw = fmaxf(iw, 0.0f);
        ih = fmaxf(ih, 0.0f);
        float inter = iw * ih;
        float denom = (ra + ca) - inter;                // reference op order
        bool pred = (denom > 0.0f) && ((double)inter > (double)denom * IOU_THR);
        unsigned long long balm = __ballot(pred);       // bit l = col cw*64+l
        if (lane == j) myword = balm;                   // lane j holds row rbase+j
    }
    mat[((size_t)n * 64 + cw) * K1 + rbase + lane] = myword;   // coalesced 512B
}

// =====================================================================
// K_greedy: 1 consumer wave + 3 producer waves streaming 16-row groups
// into a 128-row LDS ring ahead of the cursor. mat is word-major, so a
// lane's 16-row batch is 128B contiguous. Same-ring-slot groups
// (g, g+8, ...) are owned by one producer ((g&7)%3) -> in-order reuse.
// grid: 16 blocks x 256
// =====================================================================
__global__ __launch_bounds__(256) void k_greedy(
        const unsigned long long* __restrict__ mat, int* __restrict__ skept) {
    const int n = blockIdx.x;
    int* kp = skept + n * K2;
    const int tid = threadIdx.x, lane = tid & 63, wv = tid >> 6;
    __shared__ unsigned long long ring[RING_ROWS * 64];   // 64 KB
    __shared__ int ctl[2];                                // 0: cursor hint, 1: done
    __shared__ int grp[NGRP];                             // group-loaded flags
    volatile int* vctl = ctl;
    volatile int* vgrp = grp;
    for (int k = tid; k < K2; k += 256) kp[k] = -1;
    for (int k = tid; k < NGRP; k += 256) grp[k] = 0;
    if (tid == 0) { ctl[0] = 0; ctl[1] = 0; }
    __syncthreads();

    if (wv > 0) {
        const int pw = wv - 1;                            // 0..2
        const unsigned long long* Mw = mat + ((size_t)n * 64 + lane) * (size_t)K1;
        for (int g = 0; g < NGRP; ++g) {
            if (((g & 7) % 3) != pw) continue;            // slot-chain ownership
            int hint;
            for (;;) {
                if (vctl[1]) return;
                hint = vctl[0];
                if (GRP * g <= hint + (RING_ROWS - GRP)) break;
                __builtin_amdgcn_s_sleep(2);
            }
            if (hint >= GRP * g + GRP) continue;          // cursor already past group
            const ulonglong2* p = (const ulonglong2*)(Mw + GRP * g);
            ulonglong2 tt[8];
            #pragma unroll
            for (int i = 0; i < 8; ++i) tt[i] = p[i];
            const int base = (GRP * g) & (RING_ROWS - 1);
            #pragma unroll
            for (int i = 0; i < 8; ++i) {
                ring[(base + 2 * i    ) * 64 + lane] = tt[i].x;
                ring[(base + 2 * i + 1) * 64 + lane] = tt[i].y;
            }
            __asm__ __volatile__("s_waitcnt lgkmcnt(0)" ::: "memory");  // release
            if (lane == 0) vgrp[g] = 1;
        }
        return;
    }

    // consumer (wave 0)
    unsigned long long rem = 0ull;
    int cursor = 0;
    for (int it = 0; it < K2; ++it) {
        const int cwrd = cursor >> 6;
        unsigned long long avail = ~rem;
        if (lane < cwrd) avail = 0ull;
        else if (lane == cwrd) avail &= ~((1ull << (cursor & 63)) - 1ull);
        unsigned long long bal = __ballot(avail != 0ull);
        if (bal == 0ull) break;
        const int L = (int)__builtin_ctzll(bal);
        unsigned long long aL = __shfl(avail, L);
        const int c = (L << 6) + (int)__builtin_ctzll(aL);
        if (lane == 0) { kp[it] = c; vctl[0] = c; }
        while (!vgrp[c >> 4]) __builtin_amdgcn_s_sleep(1);   // acquire
        __asm__ __volatile__("" ::: "memory");
        rem |= ring[(c & (RING_ROWS - 1)) * 64 + lane];
        cursor = c + 1;
    }
    if (lane == 0) vctl[1] = 1;
}

// =====================================================================
// K_final: one wave per output row: class argmax (80 gathered) + write 6.
// grid: 1200 blocks x 256
// =====================================================================
__global__ __launch_bounds__(256) void k_final(
        const int* __restrict__ skept, const unsigned int* __restrict__ sidx,
        const float* __restrict__ sscore, const float* __restrict__ cls,
        const float* __restrict__ bx1, const float* __restrict__ by1,
        const float* __restrict__ bx2, const float* __restrict__ by2,
        float* __restrict__ out) {
    const int g = blockIdx.x * 4 + (threadIdx.x >> 6);
    const int lane = threadIdx.x & 63;
    const int n = g / K2, k = g % K2;
    const int sel = skept[n * K2 + k];
    float* op = out + ((size_t)n * K2 + k) * 6;
    if (sel < 0) {
        if (lane < 6) op[lane] = 0.0f;
        return;
    }
    const unsigned int p = sidx[(size_t)n * K1 + sel];
    const int a  = (int)(p % 3u);
    const int hw = (int)(p / 3u);
    const float* cb = cls + ((size_t)n * 240 + a * 80) * HW_ + hw;
    float v = cb[(size_t)lane * HW_];
    int c = lane;
    if (lane < 16) {
        float v2 = cb[(size_t)(64 + lane) * HW_];
        if (v2 > v) { v = v2; c = 64 + lane; }
    }
    for (int off = 32; off > 0; off >>= 1) {
        float ov = __shfl_down(v, off);
        int   oc = __shfl_down(c, off);
        if ((ov > v) || (ov == v && oc < c)) { v = ov; c = oc; }
    }
    if (lane == 0) {
        op[0] = bx1[(size_t)n * K1 + sel];
        op[1] = by1[(size_t)n * K1 + sel];
        op[2] = bx2[(size_t)n * K1 + sel];
        op[3] = by2[(size_t)n * K1 + sel];
        op[4] = sscore[(size_t)n * K1 + sel];
        op[5] = (float)(c + 1);
    }
}

// =====================================================================
extern "C" void kernel_launch(void* const* d_in, const int* in_sizes, int n_in,
                              void* d_out, int out_size, void* d_ws, size_t ws_size,
                              hipStream_t stream) {
    (void)in_sizes; (void)n_in; (void)out_size; (void)ws_size;
    const float* objectness = (const float*)d_in[1];
    const float* box_reg    = (const float*)d_in[2];
    const float* cls        = (const float*)d_in[3];
    float* out = (float*)d_out;

    char* ws = (char*)d_ws;
    size_t off = 0;
    unsigned int* hist = (unsigned int*)(ws + off);       off += (size_t)NIMG * 4096 * 4;
    unsigned int* cnt  = (unsigned int*)(ws + off);       off += 64;
    unsigned int* Tarr = (unsigned int*)(ws + off);       off += 64;
    unsigned long long* cand = (unsigned long long*)(ws + off); off += (size_t)NIMG * CAND_CAP * 8;
    unsigned int* sidx = (unsigned int*)(ws + off);       off += (size_t)NIMG * K1 * 4;
    float* sscore = (float*)(ws + off);                   off += (size_t)NIMG * K1 * 4;
    float* bx1 = (float*)(ws + off);                      off += (size_t)NIMG * K1 * 4;
    float* by1 = (float*)(ws + off);                      off += (size_t)NIMG * K1 * 4;
    float* bx2 = (float*)(ws + off);                      off += (size_t)NIMG * K1 * 4;
    float* by2 = (float*)(ws + off);                      off += (size_t)NIMG * K1 * 4;
    float* bar = (float*)(ws + off);                      off += (size_t)NIMG * K1 * 4;
    unsigned long long* mat = (unsigned long long*)(ws + off); off += (size_t)NIMG * K1 * 64 * 8;
    int* skept = (int*)(ws + off);                        off += (size_t)NIMG * K2 * 4;

    hipMemsetAsync(hist, 0, (size_t)NIMG * 4096 * 4 + 64, stream);  // hist + cnt
    k_hist   <<<240, 256, 0, stream>>>(objectness, hist);
    k_thresh <<<NIMG, 64, 0, stream>>>(hist, Tarr);
    k_compact<<<NIMG * 75, 1024, 0, stream>>>(objectness, Tarr, cand, cnt);
    k_sort   <<<NIMG, 1024, 0, stream>>>(cand, cnt, sidx, sscore);
    k_decode <<<(NIMG * K1) / 256, 256, 0, stream>>>(sidx, box_reg, bx1, by1, bx2, by2, bar);
    k_iou    <<<NIMG * TRI_BLOCKS, 256, 0, stream>>>(bx1, by1, bx2, by2, bar, mat);
    k_greedy <<<NIMG, 256, 0, stream>>>(mat, skept);
    k_final  <<<NIMG * K2 / 4, 256, 0, stream>>>(skept, sidx, sscore, cls,
                                                 bx1, by1, bx2, by2, out);
}

// Round 2
// 761.433 us; speedup vs baseline: 1.0663x; 1.0156x over previous
//
#include <hip/hip_runtime.h>
#include <math.h>

#define NIMG 16
#define A_ 3
#define H_ 160
#define W_ 160
#define C_ 80
#define HW_ (H_*W_)        // 25600
#define P_ (HW_*A_)        // 76800
#define K1 4096
#define K2 300
#define CAND_CAP 8192
#define IMGMAX 639.0f
#define BBOX_CLIP 4.135166556742356f  // log(1000/16)
// 0.5 + 2^-26, exact in double. RN32(inter/denom) > 0.5  <=>  denom>0 && inter > denom*THR (exact)
#define IOU_THR (0.5 + 1.0/67108864.0)

#define RING_ROWS 128
#define GRP 16
#define NGRP (K1/GRP)      // 256
#define NTRI 2080          // 64*65/2 wave-tiles per image
#define TRI_BLOCKS 520     // NTRI / 4 waves
#define NCHUNK 15          // histogram chunks per image

__device__ __forceinline__ unsigned int f2key(float x) {
    unsigned int u = __float_as_uint(x);
    return (u & 0x80000000u) ? ~u : (u | 0x80000000u);
}
__device__ __forceinline__ float key2f(unsigned int k) {
    unsigned int u = (k & 0x80000000u) ? (k & 0x7FFFFFFFu) : ~k;
    return __uint_as_float(u);
}

// =====================================================================
// S1: per-image-chunk histogram of top-12 key bits, LDS-aggregated,
// written NON-atomically to hist[n][chunk][4096] (no global memset).
// grid: 240 blocks x 256 (15 chunks/image, 5120 items each)
// =====================================================================
__global__ __launch_bounds__(256) void k_hist(
        const float* __restrict__ obj, unsigned int* __restrict__ hist) {
    const int n = blockIdx.x / NCHUNK;
    const int chunk = blockIdx.x % NCHUNK;
    __shared__ unsigned int lh[4096];
    const int tid = threadIdx.x;
    for (int i = tid; i < 4096; i += 256) lh[i] = 0;
    __syncthreads();
    const float4* o4 = (const float4*)(obj + (size_t)n * P_ + chunk * 5120);
    for (int q = tid; q < 1280; q += 256) {
        float4 v = o4[q];
        atomicAdd(&lh[f2key(v.x) >> 20], 1u);
        atomicAdd(&lh[f2key(v.y) >> 20], 1u);
        atomicAdd(&lh[f2key(v.z) >> 20], 1u);
        atomicAdd(&lh[f2key(v.w) >> 20], 1u);
    }
    __syncthreads();
    unsigned int* hp = hist + ((size_t)n * NCHUNK + chunk) * 4096;
    for (int i = tid; i < 4096; i += 256) hp[i] = lh[i];
}

// =====================================================================
// S2: per-image threshold bucket. 16 blocks x 256.
// Sums 15 chunk-slices, 3-level suffix scan, zeroes cnt[n].
// =====================================================================
__global__ __launch_bounds__(256) void k_thresh(
        const unsigned int* __restrict__ hist, unsigned int* __restrict__ Tarr,
        unsigned int* __restrict__ cnt) {
    const int n = blockIdx.x, tid = threadIdx.x;
    const int lane = tid & 63, wv = tid >> 6;
    __shared__ unsigned int B[4096];
    __shared__ unsigned int wtot[4];
    for (int i = tid; i < 4096; i += 256) {
        unsigned int s = 0;
        for (int ch = 0; ch < NCHUNK; ++ch)
            s += hist[((size_t)n * NCHUNK + ch) * 4096 + i];
        B[i] = s;
    }
    __syncthreads();
    // thread t owns buckets [16t, 16t+16)
    unsigned int ps = 0;
    #pragma unroll
    for (int j = 0; j < 16; ++j) ps += B[16 * tid + j];
    // inclusive suffix within wave
    unsigned int t2 = ps;
    for (int off = 1; off < 64; off <<= 1) {
        unsigned int u = __shfl_down(t2, off);
        if (lane + off < 64) t2 += u;
    }
    if (lane == 0) wtot[wv] = t2;   // whole-wave total
    __syncthreads();
    unsigned int higher = 0;
    for (int w = wv + 1; w < 4; ++w) higher += wtot[w];
    const unsigned int cross = higher + t2;        // S(16t)
    const unsigned int above = cross - ps;         // S(16t+16)
    if (cross >= (unsigned)K1 && above < (unsigned)K1) {
        unsigned int r = above;
        for (int j = 15; j >= 0; --j) {
            r += B[16 * tid + j];
            if (r >= (unsigned)K1) {
                Tarr[n] = ((unsigned int)(16 * tid + j)) << 20;
                break;
            }
        }
    }
    if (tid == 0) cnt[n] = 0;
}

// =====================================================================
// S3: compaction, float4 loads, block-aggregated atomics.
// grid: 1200 blocks x 256 (4 items/thread)
// =====================================================================
__global__ __launch_bounds__(256) void k_compact(
        const float* __restrict__ obj, const unsigned int* __restrict__ Tarr,
        unsigned long long* __restrict__ cand, unsigned int* __restrict__ cnt) {
    const int n = blockIdx.x / 75;
    const int base = (blockIdx.x % 75) * 1024;
    const int tid = threadIdx.x, lane = tid & 63, wv = tid >> 6;
    const unsigned int T = Tarr[n];
    float4 v = ((const float4*)(obj + (size_t)n * P_ + base))[tid];
    unsigned int k0 = f2key(v.x), k1 = f2key(v.y), k2 = f2key(v.z), k3 = f2key(v.w);
    bool p0 = k0 >= T, p1 = k1 >= T, p2 = k2 >= T, p3 = k3 >= T;
    unsigned long long m0 = __ballot(p0), m1 = __ballot(p1),
                       m2 = __ballot(p2), m3 = __ballot(p3);
    __shared__ unsigned int s_wbase[4];
    __shared__ unsigned int s_cnt, s_start;
    if (tid == 0) s_cnt = 0;
    __syncthreads();
    unsigned int c0 = (unsigned)__popcll(m0), c1 = (unsigned)__popcll(m1),
                 c2 = (unsigned)__popcll(m2), c3 = (unsigned)__popcll(m3);
    if (lane == 0) s_wbase[wv] = atomicAdd(&s_cnt, c0 + c1 + c2 + c3);
    __syncthreads();
    if (tid == 0) s_start = atomicAdd(&cnt[n], s_cnt);
    __syncthreads();
    const unsigned int wb = s_start + s_wbase[wv];
    const unsigned long long below = (1ull << lane) - 1ull;
    const int q0 = base + tid * 4;
    unsigned int pos, q;
    #define EMIT(pi, ki, oi, qi)                                               \
        if (pi) {                                                              \
            pos = wb + (oi); q = (unsigned)(qi);                               \
            if (pos < CAND_CAP) {                                              \
                unsigned int p = (q % HW_) * A_ + (q / HW_);                   \
                cand[(size_t)n * CAND_CAP + pos] =                             \
                    ((unsigned long long)(~(ki)) << 32) | (unsigned long long)p;\
            }                                                                  \
        }
    EMIT(p0, k0, (unsigned)__popcll(m0 & below), q0 + 0)
    EMIT(p1, k1, c0 + (unsigned)__popcll(m1 & below), q0 + 1)
    EMIT(p2, k2, c0 + c1 + (unsigned)__popcll(m2 & below), q0 + 2)
    EMIT(p3, k3, c0 + c1 + c2 + (unsigned)__popcll(m3 & below), q0 + 3)
    #undef EMIT
}

// =====================================================================
// K_sort1: per-half bitonic sort of 4096 items. half0 ascending,
// half1 descending (prepares single bitonic merge). 32 blocks x 1024.
// Wave owns 256-item segment; stages j<256 barrier-free.
// =====================================================================
__global__ __launch_bounds__(1024) void k_sort1(
        const unsigned long long* __restrict__ candIn,
        const unsigned int* __restrict__ cnt,
        unsigned long long* __restrict__ candOut) {
    const int n = blockIdx.x >> 1, half = blockIdx.x & 1;
    __shared__ unsigned long long S[4096];   // 32 KB
    const int tid = threadIdx.x;
    const int wv = tid >> 6, lane = tid & 63;
    const int seg = wv * 256;
    unsigned int c = cnt[n]; if (c > CAND_CAP) c = CAND_CAP;
    const int gbase = half * 4096;
    #pragma unroll
    for (int m = 0; m < 4; ++m) {
        int t = seg + m * 64 + lane;
        int g = gbase + t;
        S[t] = (g < (int)c) ? candIn[(size_t)n * CAND_CAP + g]
                            : 0xFFFFFFFFFFFFFFFFull;
    }
    int prevCross = 1;
    for (int k = 2; k <= 4096; k <<= 1) {
        for (int j = k >> 1; j > 0; j >>= 1) {
            int cross = (j >= 256);
            if (cross || prevCross) __syncthreads();
            #pragma unroll
            for (int m = 0; m < 4; ++m) {
                int t = seg + m * 64 + lane;
                int ixj = t ^ j;
                if (ixj > t) {
                    unsigned long long a = S[t], b = S[ixj];
                    bool up = ((t & k) == 0);
                    if (half) up = !up;
                    if ((a > b) == up) { S[t] = b; S[ixj] = a; }
                }
            }
            prevCross = cross;
        }
    }
    __syncthreads();
    #pragma unroll
    for (int m = 0; m < 4; ++m) {
        int t = seg + m * 64 + lane;
        candOut[(size_t)n * CAND_CAP + gbase + t] = S[t];
    }
}

// =====================================================================
// K_sort2: 13-pass bitonic merge of the two opposed halves (ascending
// result) + FUSED epilogue: sidx/sscore + anchor decode + clip + area.
// 16 blocks x 1024.
// =====================================================================
__global__ __launch_bounds__(1024) void k_sort2(
        const unsigned long long* __restrict__ cand,
        const float* __restrict__ reg,
        unsigned int* __restrict__ sidx, float* __restrict__ sscore,
        float* __restrict__ bx1, float* __restrict__ by1,
        float* __restrict__ bx2, float* __restrict__ by2,
        float* __restrict__ bar) {
#pragma clang fp contract(off)
    const int n = blockIdx.x;
    __shared__ unsigned long long S[CAND_CAP];   // 64 KB
    const int tid = threadIdx.x;
    const int wv = tid >> 6, lane = tid & 63;
    const int seg = wv * 512;
    #pragma unroll
    for (int m = 0; m < 8; ++m) {
        int t = seg + m * 64 + lane;
        S[t] = cand[(size_t)n * CAND_CAP + t];
    }
    int prevCross = 1;
    for (int j = 4096; j > 0; j >>= 1) {     // k = 8192 stage only, up = true
        int cross = (j >= 512);
        if (cross || prevCross) __syncthreads();
        #pragma unroll
        for (int m = 0; m < 8; ++m) {
            int t = seg + m * 64 + lane;
            int ixj = t ^ j;
            if (ixj > t) {
                unsigned long long a = S[t], b = S[ixj];
                if (a > b) { S[t] = b; S[ixj] = a; }
            }
        }
        prevCross = cross;
    }
    __syncthreads();
    // epilogue: all 1024 threads, 4 items each (coalesced t = tid + 1024*i)
    #pragma unroll
    for (int i = 0; i < 4; ++i) {
        const int t = tid + 1024 * i;
        const unsigned long long s = S[t];
        const unsigned int p = (unsigned int)s;
        const size_t gid = (size_t)n * K1 + t;
        sidx[gid] = p;
        float x = key2f(~(unsigned int)(s >> 32));
        sscore[gid] = 1.0f / (1.0f + expf(-x));

        const int a  = (int)(p % 3u);
        const int hw = (int)(p / 3u);
        const int hh = hw / W_, ww = hw % W_;
        const float* rb = reg + ((size_t)n * 12 + a * 4) * HW_ + hw;
        float dx = rb[0];
        float dy = rb[HW_];
        float dw = rb[2 * HW_];
        float dh = rb[3 * HW_];

        const int half = 16 << a;
        float a0 = (float)(4 * ww + 2 - half);
        float a1 = (float)(4 * hh + 2 - half);
        float a2 = (float)(4 * ww + 2 + half - 1);
        float a3 = (float)(4 * hh + 2 + half - 1);

        float w  = a2 - a0 + 1.0f;
        float h  = a3 - a1 + 1.0f;
        float cx = a0 + 0.5f * w;
        float cy = a1 + 0.5f * h;
        float dwc = fminf(dw, BBOX_CLIP);
        float dhc = fminf(dh, BBOX_CLIP);
        float pcx = dx * w + cx;
        float pcy = dy * h + cy;
        float pw  = expf(dwc) * w;
        float ph  = expf(dhc) * h;
        float x1 = pcx - 0.5f * pw;
        float y1 = pcy - 0.5f * ph;
        float x2 = pcx + 0.5f * pw - 1.0f;
        float y2 = pcy + 0.5f * ph - 1.0f;
        x1 = fminf(fmaxf(x1, 0.0f), IMGMAX);
        y1 = fminf(fmaxf(y1, 0.0f), IMGMAX);
        x2 = fminf(fmaxf(x2, 0.0f), IMGMAX);
        y2 = fminf(fmaxf(y2, 0.0f), IMGMAX);
        bx1[gid] = x1; by1[gid] = y1; bx2[gid] = x2; by2[gid] = y2;
        bar[gid] = (x2 - x1 + 1.0f) * (y2 - y1 + 1.0f);   // reference area order
    }
}

// =====================================================================
// K_iou: triangular per-wave tiling, lane = COLUMN. Column boxes in
// registers; row boxes wave-uniform (scalar path); per-row mask via
// ballot. mat WORD-MAJOR: mat[n][word][row] -> 512B coalesced store.
// grid: NIMG*520 blocks x 256 (4 waves/block)
// =====================================================================
__global__ __launch_bounds__(256) void k_iou(
        const float* __restrict__ bx1, const float* __restrict__ by1,
        const float* __restrict__ bx2, const float* __restrict__ by2,
        const float* __restrict__ bar,
        unsigned long long* __restrict__ mat) {
#pragma clang fp contract(off)
    const int b = blockIdx.x;
    const int n = b / TRI_BLOCKS;
    const int lane = threadIdx.x & 63, wv = threadIdx.x >> 6;
    const int t = (b % TRI_BLOCKS) * 4 + wv;            // 0..2079, wave-uniform
    int cw = (int)((sqrtf(8.0f * (float)t + 1.0f) - 1.0f) * 0.5f);
    while (cw * (cw + 1) / 2 > t) --cw;
    while ((cw + 1) * (cw + 2) / 2 <= t) ++cw;
    int R = t - cw * (cw + 1) / 2;                      // 0..cw
    cw = __builtin_amdgcn_readfirstlane(cw);
    R  = __builtin_amdgcn_readfirstlane(R);

    const size_t nb = (size_t)n * K1;
    const int col = cw * 64 + lane;
    const float cx1 = bx1[nb + col];
    const float cy1 = by1[nb + col];
    const float cx2 = bx2[nb + col];
    const float cy2 = by2[nb + col];
    const float ca  = bar[nb + col];

    const int rbase = R * 64;
    unsigned long long myword = 0ull;
    #pragma unroll 4
    for (int j = 0; j < 64; ++j) {
        const int r = rbase + j;                        // wave-uniform
        const float rx1 = bx1[nb + r];
        const float ry1 = by1[nb + r];
        const float rx2 = bx2[nb + r];
        const float ry2 = by2[nb + r];
        const float ra  = bar[nb + r];
        float iw = fminf(rx2, cx2) - fmaxf(rx1, cx1) + 1.0f;
        float ih = fminf(ry2, cy2) - fmaxf(ry1, cy1) + 1.0f;
        iw = fmaxf(iw, 0.0f);
        ih = fmaxf(ih, 0.0f);
        float inter = iw * ih;
        float denom = (ra + ca) - inter;                // reference op order
        bool pred = (denom > 0.0f) && ((double)inter > (double)denom * IOU_THR);
        unsigned long long balm = __ballot(pred);       // bit l = col cw*64+l
        if (lane == j) myword = balm;                   // lane j holds row rbase+j
    }
    mat[((size_t)n * 64 + cw) * K1 + rbase + lane] = myword;   // coalesced 512B
}

// =====================================================================
// K_greedy: 1 consumer + 3 producers. Producers publish a monotone
// per-producer progress word; consumer caches progress in registers and
// speculatively issues the ring read before the check (safe: a prior
// progress observation happens-before the read). Producers skip dead
// lower-triangle words. grid: 16 blocks x 256
// =====================================================================
__global__ __launch_bounds__(256) void k_greedy(
        const unsigned long long* __restrict__ mat, int* __restrict__ skept) {
    const int n = blockIdx.x;
    int* kp = skept + n * K2;
    const int tid = threadIdx.x, lane = tid & 63, wv = tid >> 6;
    __shared__ unsigned long long ring[RING_ROWS * 64];   // 64 KB
    __shared__ int ctl[2];                                // 0: cursor hint, 1: done
    __shared__ int prog[3];                               // per-producer progress
    volatile int* vctl = ctl;
    volatile int* vprog = prog;
    for (int k = tid; k < K2; k += 256) kp[k] = -1;
    if (tid < 3) prog[tid] = -1;
    if (tid == 0) { ctl[0] = 0; ctl[1] = 0; }
    __syncthreads();

    if (wv > 0) {
        const int pw = wv - 1;                            // 0..2
        const unsigned long long* Mw = mat + ((size_t)n * 64 + lane) * (size_t)K1;
        for (int g = 0; g < NGRP; ++g) {
            if (((g & 7) % 3) != pw) continue;            // slot-chain ownership
            if (vctl[1]) return;
            int hint;
            for (;;) {
                hint = vctl[0];
                if (GRP * g <= hint + (RING_ROWS - GRP)) break;
                if (vctl[1]) return;
                __builtin_amdgcn_s_sleep(2);
            }
            if (hint >= GRP * g + GRP) {                  // cursor already past
                if (lane == 0) vprog[pw] = g;             // data never needed
                continue;
            }
            const int wmin = g >> 2;                      // words < wmin are dead
            const int base = (GRP * g) & (RING_ROWS - 1);
            if (lane >= wmin) {
                const ulonglong2* p = (const ulonglong2*)(Mw + GRP * g);
                ulonglong2 tt[8];
                #pragma unroll
                for (int i = 0; i < 8; ++i) tt[i] = p[i];
                #pragma unroll
                for (int i = 0; i < 8; ++i) {
                    ring[(base + 2 * i    ) * 64 + lane] = tt[i].x;
                    ring[(base + 2 * i + 1) * 64 + lane] = tt[i].y;
                }
            }
            __asm__ __volatile__("s_waitcnt lgkmcnt(0)" ::: "memory");  // release
            if (lane == 0) vprog[pw] = g;
        }
        return;
    }

    // consumer (wave 0)
    unsigned long long rem = 0ull;
    int cursor = 0;
    int pc0 = -1, pc1 = -1, pc2 = -1;                     // cached progress
    for (int it = 0; it < K2; ++it) {
        const int cwrd = cursor >> 6;
        unsigned long long avail = ~rem;
        if (lane < cwrd) avail = 0ull;
        else if (lane == cwrd) avail &= ~((1ull << (cursor & 63)) - 1ull);
        unsigned long long bal = __ballot(avail != 0ull);
        if (bal == 0ull) break;
        const int L = (int)__builtin_ctzll(bal);
        unsigned long long aL = __shfl(avail, L);
        const int c = (L << 6) + (int)__builtin_ctzll(aL);
        if (lane == 0) { kp[it] = c; vctl[0] = c; }
        const int g = c >> 4;
        const int owner = (g & 7) % 3;
        unsigned long long r1 = ring[(c & (RING_ROWS - 1)) * 64 + lane]; // speculative
        int pcv = (owner == 0) ? pc0 : ((owner == 1) ? pc1 : pc2);
        if (pcv < g) {
            int pv;
            while ((pv = vprog[owner]) < g) __builtin_amdgcn_s_sleep(1); // acquire
            if (owner == 0) pc0 = pv; else if (owner == 1) pc1 = pv; else pc2 = pv;
            __asm__ __volatile__("" ::: "memory");
            r1 = ring[(c & (RING_ROWS - 1)) * 64 + lane];                // re-read
        }
        rem |= r1;
        cursor = c + 1;
    }
    if (lane == 0) vctl[1] = 1;
}

// =====================================================================
// K_final: one wave per output row: class argmax (80 gathered) + write 6.
// grid: 1200 blocks x 256
// =====================================================================
__global__ __launch_bounds__(256) void k_final(
        const int* __restrict__ skept, const unsigned int* __restrict__ sidx,
        const float* __restrict__ sscore, const float* __restrict__ cls,
        const float* __restrict__ bx1, const float* __restrict__ by1,
        const float* __restrict__ bx2, const float* __restrict__ by2,
        float* __restrict__ out) {
    const int g = blockIdx.x * 4 + (threadIdx.x >> 6);
    const int lane = threadIdx.x & 63;
    const int n = g / K2, k = g % K2;
    const int sel = skept[n * K2 + k];
    float* op = out + ((size_t)n * K2 + k) * 6;
    if (sel < 0) {
        if (lane < 6) op[lane] = 0.0f;
        return;
    }
    const unsigned int p = sidx[(size_t)n * K1 + sel];
    const int a  = (int)(p % 3u);
    const int hw = (int)(p / 3u);
    const float* cb = cls + ((size_t)n * 240 + a * 80) * HW_ + hw;
    float v = cb[(size_t)lane * HW_];
    int c = lane;
    if (lane < 16) {
        float v2 = cb[(size_t)(64 + lane) * HW_];
        if (v2 > v) { v = v2; c = 64 + lane; }
    }
    for (int off = 32; off > 0; off >>= 1) {
        float ov = __shfl_down(v, off);
        int   oc = __shfl_down(c, off);
        if ((ov > v) || (ov == v && oc < c)) { v = ov; c = oc; }
    }
    if (lane == 0) {
        op[0] = bx1[(size_t)n * K1 + sel];
        op[1] = by1[(size_t)n * K1 + sel];
        op[2] = bx2[(size_t)n * K1 + sel];
        op[3] = by2[(size_t)n * K1 + sel];
        op[4] = sscore[(size_t)n * K1 + sel];
        op[5] = (float)(c + 1);
    }
}

// =====================================================================
extern "C" void kernel_launch(void* const* d_in, const int* in_sizes, int n_in,
                              void* d_out, int out_size, void* d_ws, size_t ws_size,
                              hipStream_t stream) {
    (void)in_sizes; (void)n_in; (void)out_size; (void)ws_size;
    const float* objectness = (const float*)d_in[1];
    const float* box_reg    = (const float*)d_in[2];
    const float* cls        = (const float*)d_in[3];
    float* out = (float*)d_out;

    char* ws = (char*)d_ws;
    size_t off = 0;
    unsigned int* hist = (unsigned int*)(ws + off);       off += (size_t)NIMG * NCHUNK * 4096 * 4;
    unsigned int* cnt  = (unsigned int*)(ws + off);       off += 64;
    unsigned int* Tarr = (unsigned int*)(ws + off);       off += 64;
    unsigned long long* cand = (unsigned long long*)(ws + off); off += (size_t)NIMG * CAND_CAP * 8;
    unsigned int* sidx = (unsigned int*)(ws + off);       off += (size_t)NIMG * K1 * 4;
    float* sscore = (float*)(ws + off);                   off += (size_t)NIMG * K1 * 4;
    float* bx1 = (float*)(ws + off);                      off += (size_t)NIMG * K1 * 4;
    float* by1 = (float*)(ws + off);                      off += (size_t)NIMG * K1 * 4;
    float* bx2 = (float*)(ws + off);                      off += (size_t)NIMG * K1 * 4;
    float* by2 = (float*)(ws + off);                      off += (size_t)NIMG * K1 * 4;
    float* bar = (float*)(ws + off);                      off += (size_t)NIMG * K1 * 4;
    unsigned long long* mat = (unsigned long long*)(ws + off); off += (size_t)NIMG * K1 * 64 * 8;
    int* skept = (int*)(ws + off);                        off += (size_t)NIMG * K2 * 4;

    k_hist   <<<NIMG * NCHUNK, 256, 0, stream>>>(objectness, hist);
    k_thresh <<<NIMG, 256, 0, stream>>>(hist, Tarr, cnt);
    k_compact<<<NIMG * 75, 256, 0, stream>>>(objectness, Tarr, cand, cnt);
    k_sort1  <<<NIMG * 2, 1024, 0, stream>>>(cand, cnt, cand);
    k_sort2  <<<NIMG, 1024, 0, stream>>>(cand, box_reg, sidx, sscore,
                                         bx1, by1, bx2, by2, bar);
    k_iou    <<<NIMG * TRI_BLOCKS, 256, 0, stream>>>(bx1, by1, bx2, by2, bar, mat);
    k_greedy <<<NIMG, 256, 0, stream>>>(mat, skept);
    k_final  <<<NIMG * K2 / 4, 256, 0, stream>>>(skept, sidx, sscore, cls,
                                                 bx1, by1, bx2, by2, out);
}

// Round 4
// 759.621 us; speedup vs baseline: 1.0688x; 1.0024x over previous
//
#include <hip/hip_runtime.h>
#include <math.h>

#define NIMG 16
#define A_ 3
#define H_ 160
#define W_ 160
#define C_ 80
#define HW_ (H_*W_)        // 25600
#define P_ (HW_*A_)        // 76800
#define K1 4096
#define K2 300
#define CAND_CAP 8192
#define IMGMAX 639.0f
#define BBOX_CLIP 4.135166556742356f  // log(1000/16)
// 0.5 + 2^-26, exact in double. RN32(inter/denom) > 0.5  <=>  denom>0 && inter > denom*THR (exact)
#define IOU_THR (0.5 + 1.0/67108864.0)

#define RING_ROWS 128
#define GRP 16
#define NGRP (K1/GRP)      // 256
#define NTRI 2080          // 64*65/2 wave-tiles per image
#define TRI_BLOCKS 520     // NTRI / 4 waves
#define NCHUNK 15          // histogram chunks per image

__device__ __forceinline__ unsigned int f2key(float x) {
    unsigned int u = __float_as_uint(x);
    return (u & 0x80000000u) ? ~u : (u | 0x80000000u);
}
__device__ __forceinline__ float key2f(unsigned int k) {
    unsigned int u = (k & 0x80000000u) ? (k & 0x7FFFFFFFu) : ~k;
    return __uint_as_float(u);
}

// =====================================================================
// S1: per-image-chunk histogram of top-12 key bits, LDS-aggregated,
// written NON-atomically to hist[n][chunk][4096] (no global memset).
// grid: 240 blocks x 256 (15 chunks/image, 5120 items each)
// =====================================================================
__global__ __launch_bounds__(256) void k_hist(
        const float* __restrict__ obj, unsigned int* __restrict__ hist) {
    const int n = blockIdx.x / NCHUNK;
    const int chunk = blockIdx.x % NCHUNK;
    __shared__ unsigned int lh[4096];
    const int tid = threadIdx.x;
    for (int i = tid; i < 4096; i += 256) lh[i] = 0;
    __syncthreads();
    const float4* o4 = (const float4*)(obj + (size_t)n * P_ + chunk * 5120);
    for (int q = tid; q < 1280; q += 256) {
        float4 v = o4[q];
        atomicAdd(&lh[f2key(v.x) >> 20], 1u);
        atomicAdd(&lh[f2key(v.y) >> 20], 1u);
        atomicAdd(&lh[f2key(v.z) >> 20], 1u);
        atomicAdd(&lh[f2key(v.w) >> 20], 1u);
    }
    __syncthreads();
    unsigned int* hp = hist + ((size_t)n * NCHUNK + chunk) * 4096;
    for (int i = tid; i < 4096; i += 256) hp[i] = lh[i];
}

// =====================================================================
// S2: per-image threshold bucket. 16 blocks x 256.
// Sums 15 chunk-slices, 3-level suffix scan, zeroes cnt[n].
// =====================================================================
__global__ __launch_bounds__(256) void k_thresh(
        const unsigned int* __restrict__ hist, unsigned int* __restrict__ Tarr,
        unsigned int* __restrict__ cnt) {
    const int n = blockIdx.x, tid = threadIdx.x;
    const int lane = tid & 63, wv = tid >> 6;
    __shared__ unsigned int B[4096];
    __shared__ unsigned int wtot[4];
    for (int i = tid; i < 4096; i += 256) {
        unsigned int s = 0;
        for (int ch = 0; ch < NCHUNK; ++ch)
            s += hist[((size_t)n * NCHUNK + ch) * 4096 + i];
        B[i] = s;
    }
    __syncthreads();
    // thread t owns buckets [16t, 16t+16)
    unsigned int ps = 0;
    #pragma unroll
    for (int j = 0; j < 16; ++j) ps += B[16 * tid + j];
    // inclusive suffix within wave
    unsigned int t2 = ps;
    for (int off = 1; off < 64; off <<= 1) {
        unsigned int u = __shfl_down(t2, off);
        if (lane + off < 64) t2 += u;
    }
    if (lane == 0) wtot[wv] = t2;   // whole-wave total
    __syncthreads();
    unsigned int higher = 0;
    for (int w = wv + 1; w < 4; ++w) higher += wtot[w];
    const unsigned int cross = higher + t2;        // S(16t)
    const unsigned int above = cross - ps;         // S(16t+16)
    if (cross >= (unsigned)K1 && above < (unsigned)K1) {
        unsigned int r = above;
        for (int j = 15; j >= 0; --j) {
            r += B[16 * tid + j];
            if (r >= (unsigned)K1) {
                Tarr[n] = ((unsigned int)(16 * tid + j)) << 20;
                break;
            }
        }
    }
    if (tid == 0) cnt[n] = 0;
}

// =====================================================================
// S3: compaction, float4 loads, block-aggregated atomics.
// grid: 1200 blocks x 256 (4 items/thread)
// =====================================================================
__global__ __launch_bounds__(256) void k_compact(
        const float* __restrict__ obj, const unsigned int* __restrict__ Tarr,
        unsigned long long* __restrict__ cand, unsigned int* __restrict__ cnt) {
    const int n = blockIdx.x / 75;
    const int base = (blockIdx.x % 75) * 1024;
    const int tid = threadIdx.x, lane = tid & 63, wv = tid >> 6;
    const unsigned int T = Tarr[n];
    float4 v = ((const float4*)(obj + (size_t)n * P_ + base))[tid];
    unsigned int k0 = f2key(v.x), k1 = f2key(v.y), k2 = f2key(v.z), k3 = f2key(v.w);
    bool p0 = k0 >= T, p1 = k1 >= T, p2 = k2 >= T, p3 = k3 >= T;
    unsigned long long m0 = __ballot(p0), m1 = __ballot(p1),
                       m2 = __ballot(p2), m3 = __ballot(p3);
    __shared__ unsigned int s_wbase[4];
    __shared__ unsigned int s_cnt, s_start;
    if (tid == 0) s_cnt = 0;
    __syncthreads();
    unsigned int c0 = (unsigned)__popcll(m0), c1 = (unsigned)__popcll(m1),
                 c2 = (unsigned)__popcll(m2), c3 = (unsigned)__popcll(m3);
    if (lane == 0) s_wbase[wv] = atomicAdd(&s_cnt, c0 + c1 + c2 + c3);
    __syncthreads();
    if (tid == 0) s_start = atomicAdd(&cnt[n], s_cnt);
    __syncthreads();
    const unsigned int wb = s_start + s_wbase[wv];
    const unsigned long long below = (1ull << lane) - 1ull;
    const int q0 = base + tid * 4;
    unsigned int pos, q;
    #define EMIT(pi, ki, oi, qi)                                               \
        if (pi) {                                                              \
            pos = wb + (oi); q = (unsigned)(qi);                               \
            if (pos < CAND_CAP) {                                              \
                unsigned int p = (q % HW_) * A_ + (q / HW_);                   \
                cand[(size_t)n * CAND_CAP + pos] =                             \
                    ((unsigned long long)(~(ki)) << 32) | (unsigned long long)p;\
            }                                                                  \
        }
    EMIT(p0, k0, (unsigned)__popcll(m0 & below), q0 + 0)
    EMIT(p1, k1, c0 + (unsigned)__popcll(m1 & below), q0 + 1)
    EMIT(p2, k2, c0 + c1 + (unsigned)__popcll(m2 & below), q0 + 2)
    EMIT(p3, k3, c0 + c1 + c2 + (unsigned)__popcll(m3 & below), q0 + 3)
    #undef EMIT
}

// =====================================================================
// K_sort1: per-half bitonic sort of 4096 items. half0 ascending,
// half1 descending (prepares single bitonic merge). 32 blocks x 1024.
// Wave owns 256-item segment; stages j<256 barrier-free.
// =====================================================================
__global__ __launch_bounds__(1024) void k_sort1(
        const unsigned long long* __restrict__ candIn,
        const unsigned int* __restrict__ cnt,
        unsigned long long* __restrict__ candOut) {
    const int n = blockIdx.x >> 1, half = blockIdx.x & 1;
    __shared__ unsigned long long S[4096];   // 32 KB
    const int tid = threadIdx.x;
    const int wv = tid >> 6, lane = tid & 63;
    const int seg = wv * 256;
    unsigned int c = cnt[n]; if (c > CAND_CAP) c = CAND_CAP;
    const int gbase = half * 4096;
    #pragma unroll
    for (int m = 0; m < 4; ++m) {
        int t = seg + m * 64 + lane;
        int g = gbase + t;
        S[t] = (g < (int)c) ? candIn[(size_t)n * CAND_CAP + g]
                            : 0xFFFFFFFFFFFFFFFFull;
    }
    int prevCross = 1;
    for (int k = 2; k <= 4096; k <<= 1) {
        for (int j = k >> 1; j > 0; j >>= 1) {
            int cross = (j >= 256);
            if (cross || prevCross) __syncthreads();
            #pragma unroll
            for (int m = 0; m < 4; ++m) {
                int t = seg + m * 64 + lane;
                int ixj = t ^ j;
                if (ixj > t) {
                    unsigned long long a = S[t], b = S[ixj];
                    bool up = ((t & k) == 0);
                    if (half) up = !up;
                    if ((a > b) == up) { S[t] = b; S[ixj] = a; }
                }
            }
            prevCross = cross;
        }
    }
    __syncthreads();
    #pragma unroll
    for (int m = 0; m < 4; ++m) {
        int t = seg + m * 64 + lane;
        candOut[(size_t)n * CAND_CAP + gbase + t] = S[t];
    }
}

// =====================================================================
// K_sort2: 13-pass bitonic merge of the two opposed halves (ascending
// result) + FUSED epilogue: sidx/sscore + anchor decode + clip + area,
// boxes packed as float4. 16 blocks x 1024.
// =====================================================================
__global__ __launch_bounds__(1024) void k_sort2(
        const unsigned long long* __restrict__ cand,
        const float* __restrict__ reg,
        unsigned int* __restrict__ sidx, float* __restrict__ sscore,
        float4* __restrict__ bpak, float* __restrict__ bar) {
#pragma clang fp contract(off)
    const int n = blockIdx.x;
    __shared__ unsigned long long S[CAND_CAP];   // 64 KB
    const int tid = threadIdx.x;
    const int wv = tid >> 6, lane = tid & 63;
    const int seg = wv * 512;
    #pragma unroll
    for (int m = 0; m < 8; ++m) {
        int t = seg + m * 64 + lane;
        S[t] = cand[(size_t)n * CAND_CAP + t];
    }
    int prevCross = 1;
    for (int j = 4096; j > 0; j >>= 1) {     // k = 8192 stage only, up = true
        int cross = (j >= 512);
        if (cross || prevCross) __syncthreads();
        #pragma unroll
        for (int m = 0; m < 8; ++m) {
            int t = seg + m * 64 + lane;
            int ixj = t ^ j;
            if (ixj > t) {
                unsigned long long a = S[t], b = S[ixj];
                if (a > b) { S[t] = b; S[ixj] = a; }
            }
        }
        prevCross = cross;
    }
    __syncthreads();
    // epilogue: all 1024 threads, 4 items each (coalesced t = tid + 1024*i)
    #pragma unroll
    for (int i = 0; i < 4; ++i) {
        const int t = tid + 1024 * i;
        const unsigned long long s = S[t];
        const unsigned int p = (unsigned int)s;
        const size_t gid = (size_t)n * K1 + t;
        sidx[gid] = p;
        float x = key2f(~(unsigned int)(s >> 32));
        sscore[gid] = 1.0f / (1.0f + expf(-x));

        const int a  = (int)(p % 3u);
        const int hw = (int)(p / 3u);
        const int hh = hw / W_, ww = hw % W_;
        const float* rb = reg + ((size_t)n * 12 + a * 4) * HW_ + hw;
        float dx = rb[0];
        float dy = rb[HW_];
        float dw = rb[2 * HW_];
        float dh = rb[3 * HW_];

        const int half = 16 << a;
        float a0 = (float)(4 * ww + 2 - half);
        float a1 = (float)(4 * hh + 2 - half);
        float a2 = (float)(4 * ww + 2 + half - 1);
        float a3 = (float)(4 * hh + 2 + half - 1);

        float w  = a2 - a0 + 1.0f;
        float h  = a3 - a1 + 1.0f;
        float cx = a0 + 0.5f * w;
        float cy = a1 + 0.5f * h;
        float dwc = fminf(dw, BBOX_CLIP);
        float dhc = fminf(dh, BBOX_CLIP);
        float pcx = dx * w + cx;
        float pcy = dy * h + cy;
        float pw  = expf(dwc) * w;
        float ph  = expf(dhc) * h;
        float x1 = pcx - 0.5f * pw;
        float y1 = pcy - 0.5f * ph;
        float x2 = pcx + 0.5f * pw - 1.0f;
        float y2 = pcy + 0.5f * ph - 1.0f;
        x1 = fminf(fmaxf(x1, 0.0f), IMGMAX);
        y1 = fminf(fmaxf(y1, 0.0f), IMGMAX);
        x2 = fminf(fmaxf(x2, 0.0f), IMGMAX);
        y2 = fminf(fmaxf(y2, 0.0f), IMGMAX);
        float4 b4; b4.x = x1; b4.y = y1; b4.z = x2; b4.w = y2;
        bpak[gid] = b4;
        bar[gid] = (x2 - x1 + 1.0f) * (y2 - y1 + 1.0f);   // reference area order
    }
}

// =====================================================================
// K_iou: triangular per-wave tiling, lane = COLUMN. Column boxes in
// registers (1 dwordx4 + 1 dword); row boxes wave-uniform (scalar path,
// 1 dwordx4 + 1 dword). Per-row mask via ballot. mat WORD-MAJOR:
// mat[n][word][row] -> 512B coalesced store.
// grid: NIMG*520 blocks x 256 (4 waves/block)
// =====================================================================
__global__ __launch_bounds__(256) void k_iou(
        const float4* __restrict__ bpak, const float* __restrict__ bar,
        unsigned long long* __restrict__ mat) {
#pragma clang fp contract(off)
    const int b = blockIdx.x;
    const int n = b / TRI_BLOCKS;
    const int lane = threadIdx.x & 63, wv = threadIdx.x >> 6;
    const int t = (b % TRI_BLOCKS) * 4 + wv;            // 0..2079, wave-uniform
    int cw = (int)((sqrtf(8.0f * (float)t + 1.0f) - 1.0f) * 0.5f);
    while (cw * (cw + 1) / 2 > t) --cw;
    while ((cw + 1) * (cw + 2) / 2 <= t) ++cw;
    int R = t - cw * (cw + 1) / 2;                      // 0..cw
    cw = __builtin_amdgcn_readfirstlane(cw);
    R  = __builtin_amdgcn_readfirstlane(R);

    const size_t nb = (size_t)n * K1;
    const int col = cw * 64 + lane;
    const float4 cb = bpak[nb + col];
    const float ca  = bar[nb + col];

    const int rbase = R * 64;
    const float4* rp = bpak + nb + rbase;
    const float*  ap = bar + nb + rbase;
    unsigned long long myword = 0ull;
    #pragma unroll 8
    for (int j = 0; j < 64; ++j) {
        const float4 rb = rp[j];                        // wave-uniform
        const float  ra = ap[j];
        float iw = fminf(rb.z, cb.z) - fmaxf(rb.x, cb.x) + 1.0f;
        float ih = fminf(rb.w, cb.w) - fmaxf(rb.y, cb.y) + 1.0f;
        iw = fmaxf(iw, 0.0f);
        ih = fmaxf(ih, 0.0f);
        float inter = iw * ih;
        float denom = (ra + ca) - inter;                // reference op order
        bool pred = (denom > 0.0f) && ((double)inter > (double)denom * IOU_THR);
        unsigned long long balm = __ballot(pred);       // bit l = col cw*64+l
        if (lane == j) myword = balm;                   // lane j holds row rbase+j
    }
    mat[((size_t)n * 64 + cw) * K1 + rbase + lane] = myword;   // coalesced 512B
}

// =====================================================================
// K_greedy: 1 consumer + 3 producers, 2-pick speculation in consumer.
// DEADLOCK FIX vs R3: after r1 is resolved, the consumer drains its LDS
// queue and publishes hint = c2 BEFORE waiting for g2's data. Rows <= c1
// are consumed and rows in (c1,c2) are unavailable by construction (and
// if c2 is rejected, the next pick is provably > c2), so advancing the
// hint keeps the ring-reuse invariant while opening the producer window
// that R3 kept closed (hint stuck at c1 while waiting for far-ahead c2).
// grid: 16 blocks x 256
// =====================================================================
__global__ __launch_bounds__(256) void k_greedy(
        const unsigned long long* __restrict__ mat, int* __restrict__ skept) {
    const int n = blockIdx.x;
    int* kp = skept + n * K2;
    const int tid = threadIdx.x, lane = tid & 63, wv = tid >> 6;
    __shared__ unsigned long long ring[RING_ROWS * 64];   // 64 KB
    __shared__ int ctl[2];                                // 0: cursor hint, 1: done
    __shared__ int prog[3];                               // per-producer progress
    volatile int* vctl = ctl;
    volatile int* vprog = prog;
    for (int k = tid; k < K2; k += 256) kp[k] = -1;
    if (tid < 3) prog[tid] = -1;
    if (tid == 0) { ctl[0] = 0; ctl[1] = 0; }
    __syncthreads();

    if (wv > 0) {
        const int pw = wv - 1;                            // 0..2
        const unsigned long long* Mw = mat + ((size_t)n * 64 + lane) * (size_t)K1;
        for (int g = 0; g < NGRP; ++g) {
            if (((g & 7) % 3) != pw) continue;            // slot-chain ownership
            if (vctl[1]) return;
            int hint;
            for (;;) {
                hint = vctl[0];
                if (GRP * g <= hint + (RING_ROWS - GRP)) break;
                if (vctl[1]) return;
                __builtin_amdgcn_s_sleep(2);
            }
            if (hint >= GRP * g + GRP) {                  // cursor already past
                if (lane == 0) vprog[pw] = g;             // data never needed
                continue;
            }
            const int wmin = g >> 2;                      // words < wmin are dead
            const int base = (GRP * g) & (RING_ROWS - 1);
            if (lane >= wmin) {
                const ulonglong2* p = (const ulonglong2*)(Mw + GRP * g);
                ulonglong2 tt[8];
                #pragma unroll
                for (int i = 0; i < 8; ++i) tt[i] = p[i];
                #pragma unroll
                for (int i = 0; i < 8; ++i) {
                    ring[(base + 2 * i    ) * 64 + lane] = tt[i].x;
                    ring[(base + 2 * i + 1) * 64 + lane] = tt[i].y;
                }
            }
            __asm__ __volatile__("s_waitcnt lgkmcnt(0)" ::: "memory");  // release
            if (lane == 0) vprog[pw] = g;
        }
        return;
    }

    // consumer (wave 0)
    unsigned long long rem = 0ull;
    int cursor = 0;
    int pc[3] = {-1, -1, -1};                             // cached progress
    int it = 0;
    while (it < K2) {
        const int cwrd = cursor >> 6;
        unsigned long long avail = ~rem;
        if (lane < cwrd) avail = 0ull;
        else if (lane == cwrd) avail &= ~((1ull << (cursor & 63)) - 1ull);
        unsigned long long bal = __ballot(avail != 0ull);
        if (bal == 0ull) break;
        const int L1 = (int)__builtin_ctzll(bal);
        unsigned long long aL1 = __shfl(avail, L1);
        const int c1 = (L1 << 6) + (int)__builtin_ctzll(aL1);
        // speculative second pick (next available ignoring mask(c1))
        unsigned long long avail2 = avail;
        if (lane == L1) avail2 &= avail2 - 1;             // clear c1's bit
        unsigned long long bal2 = __ballot(avail2 != 0ull);
        int c2 = -1;
        if (bal2 != 0ull && it + 1 < K2) {
            const int L2 = (int)__builtin_ctzll(bal2);
            unsigned long long aL2 = __shfl(avail2, L2);
            c2 = (L2 << 6) + (int)__builtin_ctzll(aL2);
        }
        if (lane == 0) { kp[it] = c1; vctl[0] = c1; }
        // ring read for c1 (speculative wrt producer progress)
        const int g1 = c1 >> 4, own1 = (g1 & 7) % 3;
        unsigned long long r1 = ring[(c1 & (RING_ROWS - 1)) * 64 + lane];
        if (pc[own1] < g1) {
            int pv;
            while ((pv = vprog[own1]) < g1) __builtin_amdgcn_s_sleep(1);
            pc[own1] = pv;
            __asm__ __volatile__("" ::: "memory");
            r1 = ring[(c1 & (RING_ROWS - 1)) * 64 + lane];
        }
        if (c2 >= 0) {
            // Drain r1's LDS read, then advance hint to c2 BEFORE the g2
            // wait (deadlock fix; see header comment).
            __asm__ __volatile__("s_waitcnt lgkmcnt(0)" ::: "memory");
            if (lane == 0) vctl[0] = c2;
            const int g2 = c2 >> 4, own2 = (g2 & 7) % 3;
            unsigned long long r2 = ring[(c2 & (RING_ROWS - 1)) * 64 + lane];
            if (pc[own2] < g2) {
                int pv;
                while ((pv = vprog[own2]) < g2) __builtin_amdgcn_s_sleep(1);
                pc[own2] = pv;
                __asm__ __volatile__("" ::: "memory");
                r2 = ring[(c2 & (RING_ROWS - 1)) * 64 + lane];
            }
            // is c2 suppressed by mask(c1)?
            unsigned long long wsel = __shfl(r1, c2 >> 6);
            const bool supp = (wsel >> (c2 & 63)) & 1ull;
            rem |= r1;
            if (!supp) {
                rem |= r2;
                if (lane == 0) kp[it + 1] = c2;           // hint already = c2
                cursor = c2 + 1;
                it += 2;
            } else {
                cursor = c1 + 1;
                it += 1;
            }
        } else {
            rem |= r1;
            cursor = c1 + 1;
            it += 1;
        }
    }
    if (lane == 0) vctl[1] = 1;
}

// =====================================================================
// K_final: one wave per output row: class argmax (80 gathered) + write 6.
// grid: 1200 blocks x 256
// =====================================================================
__global__ __launch_bounds__(256) void k_final(
        const int* __restrict__ skept, const unsigned int* __restrict__ sidx,
        const float* __restrict__ sscore, const float* __restrict__ cls,
        const float4* __restrict__ bpak, float* __restrict__ out) {
    const int g = blockIdx.x * 4 + (threadIdx.x >> 6);
    const int lane = threadIdx.x & 63;
    const int n = g / K2, k = g % K2;
    const int sel = skept[n * K2 + k];
    float* op = out + ((size_t)n * K2 + k) * 6;
    if (sel < 0) {
        if (lane < 6) op[lane] = 0.0f;
        return;
    }
    const unsigned int p = sidx[(size_t)n * K1 + sel];
    const int a  = (int)(p % 3u);
    const int hw = (int)(p / 3u);
    const float* cb = cls + ((size_t)n * 240 + a * 80) * HW_ + hw;
    float v = cb[(size_t)lane * HW_];
    int c = lane;
    if (lane < 16) {
        float v2 = cb[(size_t)(64 + lane) * HW_];
        if (v2 > v) { v = v2; c = 64 + lane; }
    }
    for (int off = 32; off > 0; off >>= 1) {
        float ov = __shfl_down(v, off);
        int   oc = __shfl_down(c, off);
        if ((ov > v) || (ov == v && oc < c)) { v = ov; c = oc; }
    }
    if (lane == 0) {
        float4 b4 = bpak[(size_t)n * K1 + sel];
        op[0] = b4.x;
        op[1] = b4.y;
        op[2] = b4.z;
        op[3] = b4.w;
        op[4] = sscore[(size_t)n * K1 + sel];
        op[5] = (float)(c + 1);
    }
}

// =====================================================================
extern "C" void kernel_launch(void* const* d_in, const int* in_sizes, int n_in,
                              void* d_out, int out_size, void* d_ws, size_t ws_size,
                              hipStream_t stream) {
    (void)in_sizes; (void)n_in; (void)out_size; (void)ws_size;
    const float* objectness = (const float*)d_in[1];
    const float* box_reg    = (const float*)d_in[2];
    const float* cls        = (const float*)d_in[3];
    float* out = (float*)d_out;

    char* ws = (char*)d_ws;
    size_t off = 0;
    unsigned int* hist = (unsigned int*)(ws + off);       off += (size_t)NIMG * NCHUNK * 4096 * 4;
    unsigned int* cnt  = (unsigned int*)(ws + off);       off += 64;
    unsigned int* Tarr = (unsigned int*)(ws + off);       off += 64;
    unsigned long long* cand = (unsigned long long*)(ws + off); off += (size_t)NIMG * CAND_CAP * 8;
    unsigned int* sidx = (unsigned int*)(ws + off);       off += (size_t)NIMG * K1 * 4;
    float* sscore = (float*)(ws + off);                   off += (size_t)NIMG * K1 * 4;
    float4* bpak = (float4*)(ws + off);                   off += (size_t)NIMG * K1 * 16;
    float* bar = (float*)(ws + off);                      off += (size_t)NIMG * K1 * 4;
    unsigned long long* mat = (unsigned long long*)(ws + off); off += (size_t)NIMG * K1 * 64 * 8;
    int* skept = (int*)(ws + off);                        off += (size_t)NIMG * K2 * 4;

    k_hist   <<<NIMG * NCHUNK, 256, 0, stream>>>(objectness, hist);
    k_thresh <<<NIMG, 256, 0, stream>>>(hist, Tarr, cnt);
    k_compact<<<NIMG * 75, 256, 0, stream>>>(objectness, Tarr, cand, cnt);
    k_sort1  <<<NIMG * 2, 1024, 0, stream>>>(cand, cnt, cand);
    k_sort2  <<<NIMG, 1024, 0, stream>>>(cand, box_reg, sidx, sscore, bpak, bar);
    k_iou    <<<NIMG * TRI_BLOCKS, 256, 0, stream>>>(bpak, bar, mat);
    k_greedy <<<NIMG, 256, 0, stream>>>(mat, skept);
    k_final  <<<NIMG * K2 / 4, 256, 0, stream>>>(skept, sidx, sscore, cls,
                                                 bpak, out);
}